// Round 6
// baseline (18810.434 us; speedup 1.0000x reference)
//
#include <hip/hip_runtime.h>
#include <hip/hip_bf16.h>

// Bidirectional LSTM w/ field gates. B=128,T=256,I=H=1024,F=64. FP32 I/O.
// Round 6: single persistent cooperative kernel for the whole recurrence.
// Evidence: R3 vs R5 showed per-step time (~41us) independent of K -> per-
// dispatch overhead dominated. Now: 1 block/CU owns (dir, 8 units, all 128
// batches); Whh slice in LDS (loaded once); Wih slice from L2; Wfp in regs;
// c in VGPRs across all steps; h double-buffered bf16 in ws; one device-scope
// barrier per step (counter + __threadfence, cooperative launch).

#define Bn 128
#define Tn 256
#define In 1024
#define Hn 1024
#define Fn 64
#define NBLK 256
#define UPB 8          // units per block
#define CNT_STRIDE 16  // ints per barrier counter (64B line pad)

typedef __attribute__((ext_vector_type(8))) short short8;
typedef __attribute__((ext_vector_type(4))) short short4v;
typedef __attribute__((ext_vector_type(4))) float f32x4;

__device__ __forceinline__ unsigned short f2bf(float f) {
  __hip_bfloat16 h = __float2bfloat16(f);
  return *reinterpret_cast<unsigned short*>(&h);
}
__device__ __forceinline__ float sigm(float x) { return 1.0f / (1.0f + __expf(-x)); }
__device__ __forceinline__ float tanh_(float x) { return 1.0f - 2.0f / (1.0f + __expf(2.0f * x)); }

__global__ void f32_to_bf16_vec(const float* __restrict__ src, short* __restrict__ dst, int n4) {
  for (int i = blockIdx.x * blockDim.x + threadIdx.x; i < n4; i += gridDim.x * blockDim.x) {
    const float4 v = ((const float4*)src)[i];
    short4v o;
    o[0] = (short)f2bf(v.x); o[1] = (short)f2bf(v.y);
    o[2] = (short)f2bf(v.z); o[3] = (short)f2bf(v.w);
    ((short4v*)dst)[i] = o;
  }
}

// zero barrier counters + h parity-0 buffer (re-run every call; ws is poisoned)
__global__ void init_state(int* __restrict__ cnts, unsigned int* __restrict__ h0w) {
  const int i = blockIdx.x * blockDim.x + threadIdx.x;
  if (i < Tn * CNT_STRIDE) cnts[i] = 0;
  if (i < (2 * Bn * Hn) / 2) h0w[i] = 0u;  // parity-0: [2 dirs][128][1024] bf16
}

// Persistent kernel. grid 256 blocks x 512 thr. block: dir = bx>>7,
// utile = bx&127 -> units j0..j0+7 (32 gate-cols: c = gate*8 + unit), all 128
// batches (8 m-frags, one per wave).
__global__ __launch_bounds__(512) void lstm_persist(
    const short* __restrict__ seq_bf, const short* __restrict__ fpos_bf,
    const short* __restrict__ Wih_f, const short* __restrict__ Whh_f,
    const short* __restrict__ Wfp_f,
    const short* __restrict__ Wih_b, const short* __restrict__ Whh_b,
    const short* __restrict__ Wfp_b,
    const float* __restrict__ b_f,  const float* __restrict__ bfp_f,
    const float* __restrict__ b_b,  const float* __restrict__ bfp_b,
    short* __restrict__ h_buf,      // [parity][dir][128][1024] bf16
    int* __restrict__ cnts,
    float* __restrict__ out)
{
  const int bx = blockIdx.x;
  const int dir = bx >> 7;
  const int utile = bx & 127;
  const int j0 = utile * UPB;
  const int tid = threadIdx.x;
  const int lane = tid & 63, w = tid >> 6;
  const int l15 = lane & 15, lk = lane >> 4;

  const short* Wih_g = dir ? Wih_b : Wih_f;
  const short* Whh_g = dir ? Whh_b : Whh_f;
  const short* Wfp_g = dir ? Wfp_b : Wfp_f;
  const float* bg    = dir ? b_b   : b_f;
  const float* bfpg  = dir ? bfp_b : bfp_f;

  __shared__ short whh_s[32][1032];   // 66 KB: rows = gate-cols c, padded
  __shared__ float xch[128][33];      // 16.9 KB gate exchange
  __shared__ float fxch[128][17];     // 8.7 KB field exchange  (total ~90 KB -> 1 blk/CU)

  // ---- stage Whh slice into LDS (once) ----
  {
    const int row = tid >> 4;                   // 0..31 (gate-col c)
    const int cb = (tid & 15) * 64;
    const int grow = (row >> 3) * Hn + j0 + (row & 7);
#pragma unroll
    for (int i = 0; i < 8; ++i)
      *(short8*)&whh_s[row][cb + i * 8] =
          *(const short8*)(Whh_g + (size_t)grow * In + cb + i * 8);
  }
  // ---- Wfp B-fragments in registers (K=64 -> 2 iters) ----
  short8 bq[2];
  {
    const int frow = (l15 < 8) ? (j0 + l15) : (Hn + j0 + (l15 - 8));
#pragma unroll
    for (int it = 0; it < 2; ++it)
      bq[it] = *(const short8*)(Wfp_g + (size_t)frow * Fn + it * 32 + lk * 8);
  }
  // ---- per-thread pointwise constants (unit jj fixed per thread) ----
  const int u = tid & 7;
  const int jj = j0 + u;
  const float bi = bg[jj], bff = bg[Hn + jj], bgg = bg[2 * Hn + jj], bo = bg[3 * Hn + jj];
  const float bl = bfpg[jj], bd = bfpg[Hn + jj];
  float creg[2] = {0.f, 0.f};

  // ---- t-independent fragment pointers ----
  const int abat = w * 16 + l15;                           // A row = batch
  const int c0 = l15, c1 = 16 + l15;                       // gate-cols of frags
  const short* wxp0 = Wih_g + (size_t)((c0 >> 3) * Hn + j0 + (c0 & 7)) * In + lk * 8;
  const short* wxp1 = Wih_g + (size_t)((c1 >> 3) * Hn + j0 + (c1 & 7)) * In + lk * 8;
  const short* hb0 = &whh_s[c0][lk * 8];
  const short* hb1 = &whh_s[c1][lk * 8];

  __syncthreads();

  const size_t OUTN = (size_t)Tn * Bn * 2 * Hn;

  for (int s = 0; s < Tn; ++s) {
    const int t = dir ? (Tn - 1 - s) : s;
    const int pr = s & 1, pw = pr ^ 1;

    f32x4 acc0 = (f32x4){0.f, 0.f, 0.f, 0.f};
    f32x4 acc1 = (f32x4){0.f, 0.f, 0.f, 0.f};

    // x-part: K = 1024, B from global (L2-resident slice)
    const short* xrow = seq_bf + ((size_t)abat * Tn + t) * In + lk * 8;
    for (int k = 0; k < In; k += 32) {
      const short8 a = *(const short8*)(xrow + k);
      acc0 = __builtin_amdgcn_mfma_f32_16x16x32_bf16(a, *(const short8*)(wxp0 + k), acc0, 0, 0, 0);
      acc1 = __builtin_amdgcn_mfma_f32_16x16x32_bf16(a, *(const short8*)(wxp1 + k), acc1, 0, 0, 0);
    }
    // h-part: K = 1024, B from LDS
    const short* hrow = h_buf + (((size_t)pr * 2 + dir) * Bn + abat) * Hn + lk * 8;
    for (int k = 0; k < Hn; k += 32) {
      const short8 a = *(const short8*)(hrow + k);
      acc0 = __builtin_amdgcn_mfma_f32_16x16x32_bf16(a, *(const short8*)(hb0 + k), acc0, 0, 0, 0);
      acc1 = __builtin_amdgcn_mfma_f32_16x16x32_bf16(a, *(const short8*)(hb1 + k), acc1, 0, 0, 0);
    }
    // field-part: K = 64
    f32x4 accf = (f32x4){0.f, 0.f, 0.f, 0.f};
    const short* frow = fpos_bf + ((size_t)abat * Tn + t) * Fn + lk * 8;
    accf = __builtin_amdgcn_mfma_f32_16x16x32_bf16(*(const short8*)frow, bq[0], accf, 0, 0, 0);
    accf = __builtin_amdgcn_mfma_f32_16x16x32_bf16(*(const short8*)(frow + 32), bq[1], accf, 0, 0, 0);

    // exchange (previous readers finished before last barrier)
#pragma unroll
    for (int r = 0; r < 4; ++r) {
      const int brow = w * 16 + lk * 4 + r;
      xch[brow][l15] = acc0[r];
      xch[brow][16 + l15] = acc1[r];
      fxch[brow][l15] = accf[r];
    }
    __syncthreads();

    // pointwise: 2 (bat,unit) pairs per thread, c in registers
#pragma unroll
    for (int q2 = 0; q2 < 2; ++q2) {
      const int bat = (tid >> 3) + q2 * 64;
      const float i_g = sigm (xch[bat][u] + bi);
      const float f_g = sigm (xch[bat][8 + u] + bff);
      const float g_g = tanh_(xch[bat][16 + u] + bgg);
      const float o_g = sigm (xch[bat][24 + u] + bo);
      const float l_g = sigm (fxch[bat][u] + bl);
      const float d_g = tanh_(fxch[bat][8 + u] + bd);
      const float c_new = f_g * creg[q2] + i_g * g_g + l_g * d_g;
      const float h_new = o_g * tanh_(c_new);
      creg[q2] = c_new;
      h_buf[(((size_t)pw * 2 + dir) * Bn + bat) * Hn + jj] = (short)f2bf(h_new);
      out[((size_t)t * Bn + bat) * (2 * Hn) + (size_t)dir * Hn + jj] = h_new;
      if (s == Tn - 1) {
        out[OUTN + ((size_t)dir * Bn + bat) * Hn + jj] = h_new;
        out[OUTN + (size_t)2 * Bn * Hn + ((size_t)dir * Bn + bat) * Hn + jj] = c_new;
      }
    }

    // device-wide barrier (publish h) — skip after last step
    if (s < Tn - 1) {
      __syncthreads();
      if (tid == 0) {
        __threadfence();                       // release: flush this XCD's L2
        atomicAdd(&cnts[s * CNT_STRIDE], 1);
        while (__hip_atomic_load(&cnts[s * CNT_STRIDE], __ATOMIC_RELAXED,
                                 __HIP_MEMORY_SCOPE_AGENT) < NBLK)
          __builtin_amdgcn_s_sleep(1);
      }
      __syncthreads();
      __threadfence();                         // acquire: invalidate stale lines
    }
  }
}

static inline void conv(const void* src, short* dst, size_t n, hipStream_t stream) {
  int n4 = (int)(n / 4);
  int blocks = (n4 + 255) / 256; if (blocks > 8192) blocks = 8192;
  hipLaunchKernelGGL(f32_to_bf16_vec, dim3(blocks), dim3(256), 0, stream,
                     (const float*)src, dst, n4);
}

extern "C" void kernel_launch(void* const* d_in, const int* in_sizes, int n_in,
                              void* d_out, int out_size, void* d_ws, size_t ws_size,
                              hipStream_t stream) {
  (void)in_sizes; (void)n_in; (void)out_size; (void)ws_size;
  const float* b_f   = (const float*)d_in[4];
  const float* bfp_f = (const float*)d_in[6];
  const float* b_b   = (const float*)d_in[9];
  const float* bfp_b = (const float*)d_in[11];

  char* p = (char*)d_ws;
  int*   cnts  = (int*)p;                p += (size_t)Tn * CNT_STRIDE * 4;
  short* h_buf = (short*)p;              p += (size_t)2 * 2 * Bn * Hn * 2;   // [parity][dir][B][H]
  short* seq_bf  = (short*)p;            p += (size_t)Bn * Tn * In * 2;
  short* fpos_bf = (short*)p;            p += (size_t)Bn * Tn * Fn * 2;
  short *Wih_bf[2], *Whh_bf[2], *Wfp_bf[2];
  for (int d = 0; d < 2; ++d) { Wih_bf[d] = (short*)p; p += (size_t)4 * Hn * In * 2; }
  for (int d = 0; d < 2; ++d) { Whh_bf[d] = (short*)p; p += (size_t)4 * Hn * Hn * 2; }
  for (int d = 0; d < 2; ++d) { Wfp_bf[d] = (short*)p; p += (size_t)2 * Hn * Fn * 2; }
  float* out = (float*)d_out;

  conv(d_in[0],  seq_bf,    (size_t)Bn * Tn * In, stream);
  conv(d_in[1],  fpos_bf,   (size_t)Bn * Tn * Fn, stream);
  conv(d_in[2],  Wih_bf[0], (size_t)4 * Hn * In, stream);
  conv(d_in[3],  Whh_bf[0], (size_t)4 * Hn * Hn, stream);
  conv(d_in[5],  Wfp_bf[0], (size_t)2 * Hn * Fn, stream);
  conv(d_in[7],  Wih_bf[1], (size_t)4 * Hn * In, stream);
  conv(d_in[8],  Whh_bf[1], (size_t)4 * Hn * Hn, stream);
  conv(d_in[10], Wfp_bf[1], (size_t)2 * Hn * Fn, stream);

  hipLaunchKernelGGL(init_state, dim3(512), dim3(256), 0, stream,
                     cnts, (unsigned int*)h_buf);

  void* args[] = {
    (void*)&seq_bf, (void*)&fpos_bf,
    (void*)&Wih_bf[0], (void*)&Whh_bf[0], (void*)&Wfp_bf[0],
    (void*)&Wih_bf[1], (void*)&Whh_bf[1], (void*)&Wfp_bf[1],
    (void*)&b_f, (void*)&bfp_f, (void*)&b_b, (void*)&bfp_b,
    (void*)&h_buf, (void*)&cnts, (void*)&out
  };
  hipLaunchCooperativeKernel((void*)lstm_persist, dim3(NBLK), dim3(512),
                             args, 0, stream);
}

// Round 8
// 8676.353 us; speedup vs baseline: 2.1680x; 2.1680x over previous
//
#include <hip/hip_runtime.h>
#include <hip/hip_bf16.h>

// Bidirectional LSTM w/ field gates. B=128,T=256,I=H=1024,F=64. FP32 I/O.
// Round 8 (resubmit of R7; lost to GPU acquisition timeout):
// persistent cooperative kernel, NO __threadfence. R6 counters showed the
// per-step device fence invalidated L2 (5.36GB refetch = 21MB/step ->
// 328GB/s latency-bound). Fix: h exchanged via relaxed AGENT-scope atomic
// stores/loads (only h crosses the coherence point; weights/x stay L2-warm);
// barrier = plain atomicAdd + relaxed spin; x-part GEMM computed before the
// spin to hide barrier straggle.

#define Bn 128
#define Tn 256
#define In 1024
#define Hn 1024
#define Fn 64
#define NBLK 256
#define UPB 8          // units per block
#define CNT_STRIDE 16  // ints per barrier counter (64B line pad)

typedef __attribute__((ext_vector_type(8))) short short8;
typedef __attribute__((ext_vector_type(4))) short short4v;
typedef __attribute__((ext_vector_type(4))) float f32x4;

__device__ __forceinline__ unsigned short f2bf(float f) {
  __hip_bfloat16 h = __float2bfloat16(f);
  return *reinterpret_cast<unsigned short*>(&h);
}
__device__ __forceinline__ float sigm(float x) { return 1.0f / (1.0f + __expf(-x)); }
__device__ __forceinline__ float tanh_(float x) { return 1.0f - 2.0f / (1.0f + __expf(2.0f * x)); }

__global__ void f32_to_bf16_vec(const float* __restrict__ src, short* __restrict__ dst, int n4) {
  for (int i = blockIdx.x * blockDim.x + threadIdx.x; i < n4; i += gridDim.x * blockDim.x) {
    const float4 v = ((const float4*)src)[i];
    short4v o;
    o[0] = (short)f2bf(v.x); o[1] = (short)f2bf(v.y);
    o[2] = (short)f2bf(v.z); o[3] = (short)f2bf(v.w);
    ((short4v*)dst)[i] = o;
  }
}

// zero barrier counters + h parity-0 buffer (re-run every call; ws is poisoned)
__global__ void init_state(int* __restrict__ cnts, unsigned int* __restrict__ h0w) {
  const int i = blockIdx.x * blockDim.x + threadIdx.x;
  if (i < Tn * CNT_STRIDE) cnts[i] = 0;
  if (i < (2 * Bn * Hn) / 2) h0w[i] = 0u;  // parity-0: [2 dirs][128][1024] bf16
}

// Persistent kernel. grid 256 blocks x 512 thr. block: dir = bx>>7,
// utile = bx&127 -> units j0..j0+7 (32 gate-cols: c = gate*8 + unit), all 128
// batches (8 m-frags, one per wave).
__global__ __launch_bounds__(512) void lstm_persist(
    const short* __restrict__ seq_bf, const short* __restrict__ fpos_bf,
    const short* __restrict__ Wih_f, const short* __restrict__ Whh_f,
    const short* __restrict__ Wfp_f,
    const short* __restrict__ Wih_b, const short* __restrict__ Whh_b,
    const short* __restrict__ Wfp_b,
    const float* __restrict__ b_f,  const float* __restrict__ bfp_f,
    const float* __restrict__ b_b,  const float* __restrict__ bfp_b,
    short* __restrict__ h_buf,      // [parity][dir][128][1024] bf16
    int* __restrict__ cnts,
    float* __restrict__ out)
{
  const int bx = blockIdx.x;
  const int dir = bx >> 7;
  const int utile = bx & 127;
  const int j0 = utile * UPB;
  const int tid = threadIdx.x;
  const int lane = tid & 63, w = tid >> 6;
  const int l15 = lane & 15, lk = lane >> 4;

  const short* Wih_g = dir ? Wih_b : Wih_f;
  const short* Whh_g = dir ? Whh_b : Whh_f;
  const short* Wfp_g = dir ? Wfp_b : Wfp_f;
  const float* bg    = dir ? b_b   : b_f;
  const float* bfpg  = dir ? bfp_b : bfp_f;

  __shared__ short whh_s[32][1032];   // 66 KB: rows = gate-cols c, padded
  __shared__ float xch[128][33];      // 16.9 KB gate exchange
  __shared__ float fxch[128][17];     // 8.7 KB field exchange  (~90 KB -> 1 blk/CU)

  // ---- stage Whh slice into LDS (once) ----
  {
    const int row = tid >> 4;                   // 0..31 (gate-col c)
    const int cb = (tid & 15) * 64;
    const int grow = (row >> 3) * Hn + j0 + (row & 7);
#pragma unroll
    for (int i = 0; i < 8; ++i)
      *(short8*)&whh_s[row][cb + i * 8] =
          *(const short8*)(Whh_g + (size_t)grow * In + cb + i * 8);
  }
  // ---- Wfp B-fragments in registers (K=64 -> 2 iters) ----
  short8 bq[2];
  {
    const int frow = (l15 < 8) ? (j0 + l15) : (Hn + j0 + (l15 - 8));
#pragma unroll
    for (int it = 0; it < 2; ++it)
      bq[it] = *(const short8*)(Wfp_g + (size_t)frow * Fn + it * 32 + lk * 8);
  }
  // ---- per-thread pointwise constants (unit jj fixed per thread) ----
  const int u = tid & 7;
  const int jj = j0 + u;
  const float bi = bg[jj], bff = bg[Hn + jj], bgg = bg[2 * Hn + jj], bo = bg[3 * Hn + jj];
  const float bl = bfpg[jj], bd = bfpg[Hn + jj];
  float creg[2] = {0.f, 0.f};

  // ---- t-independent fragment pointers ----
  const int abat = w * 16 + l15;                           // A row = batch
  const int c0 = l15, c1 = 16 + l15;                       // gate-cols of frags
  const short* wxp0 = Wih_g + (size_t)((c0 >> 3) * Hn + j0 + (c0 & 7)) * In + lk * 8;
  const short* wxp1 = Wih_g + (size_t)((c1 >> 3) * Hn + j0 + (c1 & 7)) * In + lk * 8;
  const short* hb0 = &whh_s[c0][lk * 8];
  const short* hb1 = &whh_s[c1][lk * 8];

  __syncthreads();

  const size_t OUTN = (size_t)Tn * Bn * 2 * Hn;

  for (int s = 0; s < Tn; ++s) {
    const int t = dir ? (Tn - 1 - s) : s;
    const int pr = s & 1, pw = pr ^ 1;

    f32x4 acc0 = (f32x4){0.f, 0.f, 0.f, 0.f};
    f32x4 acc1 = (f32x4){0.f, 0.f, 0.f, 0.f};

    // ---- x-part first (no h dependence; hides barrier wait) ----
    const short* xrow = seq_bf + ((size_t)abat * Tn + t) * In + lk * 8;
    for (int k = 0; k < In; k += 32) {
      const short8 a = *(const short8*)(xrow + k);
      acc0 = __builtin_amdgcn_mfma_f32_16x16x32_bf16(a, *(const short8*)(wxp0 + k), acc0, 0, 0, 0);
      acc1 = __builtin_amdgcn_mfma_f32_16x16x32_bf16(a, *(const short8*)(wxp1 + k), acc1, 0, 0, 0);
    }
    // field-part: K = 64
    f32x4 accf = (f32x4){0.f, 0.f, 0.f, 0.f};
    const short* frow = fpos_bf + ((size_t)abat * Tn + t) * Fn + lk * 8;
    accf = __builtin_amdgcn_mfma_f32_16x16x32_bf16(*(const short8*)frow, bq[0], accf, 0, 0, 0);
    accf = __builtin_amdgcn_mfma_f32_16x16x32_bf16(*(const short8*)(frow + 32), bq[1], accf, 0, 0, 0);

    // ---- wait for h(s) publication (skip s=0: zeros from init) ----
    if (s > 0) {
      if (tid == 0) {
        while (__hip_atomic_load(&cnts[(s - 1) * CNT_STRIDE], __ATOMIC_RELAXED,
                                 __HIP_MEMORY_SCOPE_AGENT) < NBLK)
          __builtin_amdgcn_s_sleep(2);
      }
    }
    __syncthreads();   // joins spin; also guards xch reuse from prev pointwise

    // ---- h-part: K = 1024, A via AGENT-scope loads (coherent), B from LDS ----
    const size_t hbase = (((size_t)pr * 2 + dir) * Bn + abat) * Hn + lk * 8;
    for (int k = 0; k < Hn; k += 32) {
      union { unsigned long long q[2]; short8 s8; } hu;
      hu.q[0] = __hip_atomic_load((const unsigned long long*)(h_buf + hbase + k),
                                  __ATOMIC_RELAXED, __HIP_MEMORY_SCOPE_AGENT);
      hu.q[1] = __hip_atomic_load((const unsigned long long*)(h_buf + hbase + k + 4),
                                  __ATOMIC_RELAXED, __HIP_MEMORY_SCOPE_AGENT);
      acc0 = __builtin_amdgcn_mfma_f32_16x16x32_bf16(hu.s8, *(const short8*)(hb0 + k), acc0, 0, 0, 0);
      acc1 = __builtin_amdgcn_mfma_f32_16x16x32_bf16(hu.s8, *(const short8*)(hb1 + k), acc1, 0, 0, 0);
    }

    // ---- exchange via LDS ----
#pragma unroll
    for (int r = 0; r < 4; ++r) {
      const int brow = w * 16 + lk * 4 + r;
      xch[brow][l15] = acc0[r];
      xch[brow][16 + l15] = acc1[r];
      fxch[brow][l15] = accf[r];
    }
    __syncthreads();

    // ---- pointwise: 2 (bat,unit) pairs per thread; h published via AGENT stores ----
#pragma unroll
    for (int q2 = 0; q2 < 2; ++q2) {
      const int bat = (tid >> 3) + q2 * 64;
      const float i_g = sigm (xch[bat][u] + bi);
      const float f_g = sigm (xch[bat][8 + u] + bff);
      const float g_g = tanh_(xch[bat][16 + u] + bgg);
      const float o_g = sigm (xch[bat][24 + u] + bo);
      const float l_g = sigm (fxch[bat][u] + bl);
      const float d_g = tanh_(fxch[bat][8 + u] + bd);
      const float c_new = f_g * creg[q2] + i_g * g_g + l_g * d_g;
      const float h_new = o_g * tanh_(c_new);
      creg[q2] = c_new;

      const unsigned int hb16 = (unsigned int)f2bf(h_new);
      const unsigned int partner = __shfl_down(hb16, 1);   // unit u+1, same bat
      if ((u & 1) == 0) {
        const unsigned int pack = hb16 | (partner << 16);  // little-endian: jj, jj+1
        __hip_atomic_store(
            (unsigned int*)(h_buf + (((size_t)pw * 2 + dir) * Bn + bat) * Hn + jj),
            pack, __ATOMIC_RELAXED, __HIP_MEMORY_SCOPE_AGENT);
      }
      out[((size_t)t * Bn + bat) * (2 * Hn) + (size_t)dir * Hn + jj] = h_new;
      if (s == Tn - 1) {
        out[OUTN + ((size_t)dir * Bn + bat) * Hn + jj] = h_new;
        out[OUTN + (size_t)2 * Bn * Hn + ((size_t)dir * Bn + bat) * Hn + jj] = c_new;
      }
    }

    // ---- arrive: syncthreads drains vmcnt (h stores at coherence point) ----
    if (s < Tn - 1) {
      __syncthreads();
      if (tid == 0) atomicAdd(&cnts[s * CNT_STRIDE], 1);
    }
  }
}

static inline void conv(const void* src, short* dst, size_t n, hipStream_t stream) {
  int n4 = (int)(n / 4);
  int blocks = (n4 + 255) / 256; if (blocks > 8192) blocks = 8192;
  hipLaunchKernelGGL(f32_to_bf16_vec, dim3(blocks), dim3(256), 0, stream,
                     (const float*)src, dst, n4);
}

extern "C" void kernel_launch(void* const* d_in, const int* in_sizes, int n_in,
                              void* d_out, int out_size, void* d_ws, size_t ws_size,
                              hipStream_t stream) {
  (void)in_sizes; (void)n_in; (void)out_size; (void)ws_size;
  const float* b_f   = (const float*)d_in[4];
  const float* bfp_f = (const float*)d_in[6];
  const float* b_b   = (const float*)d_in[9];
  const float* bfp_b = (const float*)d_in[11];

  char* p = (char*)d_ws;
  int*   cnts  = (int*)p;                p += (size_t)Tn * CNT_STRIDE * 4;
  short* h_buf = (short*)p;              p += (size_t)2 * 2 * Bn * Hn * 2;   // [parity][dir][B][H]
  short* seq_bf  = (short*)p;            p += (size_t)Bn * Tn * In * 2;
  short* fpos_bf = (short*)p;            p += (size_t)Bn * Tn * Fn * 2;
  short *Wih_bf[2], *Whh_bf[2], *Wfp_bf[2];
  for (int d = 0; d < 2; ++d) { Wih_bf[d] = (short*)p; p += (size_t)4 * Hn * In * 2; }
  for (int d = 0; d < 2; ++d) { Whh_bf[d] = (short*)p; p += (size_t)4 * Hn * Hn * 2; }
  for (int d = 0; d < 2; ++d) { Wfp_bf[d] = (short*)p; p += (size_t)2 * Hn * Fn * 2; }
  float* out = (float*)d_out;

  conv(d_in[0],  seq_bf,    (size_t)Bn * Tn * In, stream);
  conv(d_in[1],  fpos_bf,   (size_t)Bn * Tn * Fn, stream);
  conv(d_in[2],  Wih_bf[0], (size_t)4 * Hn * In, stream);
  conv(d_in[3],  Whh_bf[0], (size_t)4 * Hn * Hn, stream);
  conv(d_in[5],  Wfp_bf[0], (size_t)2 * Hn * Fn, stream);
  conv(d_in[7],  Wih_bf[1], (size_t)4 * Hn * In, stream);
  conv(d_in[8],  Whh_bf[1], (size_t)4 * Hn * Hn, stream);
  conv(d_in[10], Wfp_bf[1], (size_t)2 * Hn * Fn, stream);

  hipLaunchKernelGGL(init_state, dim3(512), dim3(256), 0, stream,
                     cnts, (unsigned int*)h_buf);

  void* args[] = {
    (void*)&seq_bf, (void*)&fpos_bf,
    (void*)&Wih_bf[0], (void*)&Whh_bf[0], (void*)&Wfp_bf[0],
    (void*)&Wih_bf[1], (void*)&Whh_bf[1], (void*)&Wfp_bf[1],
    (void*)&b_f, (void*)&bfp_f, (void*)&b_b, (void*)&bfp_b,
    (void*)&h_buf, (void*)&cnts, (void*)&out
  };
  hipLaunchCooperativeKernel((void*)lstm_persist, dim3(NBLK), dim3(512),
                             args, 0, stream);
}